// Round 6
// baseline (542.907 us; speedup 1.0000x reference)
//
#include <hip/hip_runtime.h>

#define NK 512
#define ND 64
#define NHW 4096
#define NPIX 131072            // 32*64*64
#define OUT_ELEMS 8388608      // 32*64*64*64
#define XS 68                  // LDS row stride in floats (16B-aligned)

// ---------------------------------------------------------------------------
// Prep: sc[k] = numpy-pairwise-8 fp32 sum of fl(c_d^2); zero the two loss
// slots (harness re-poisons d_out/d_ws to 0xAA before every timed replay).
// ---------------------------------------------------------------------------
__global__ __launch_bounds__(256) void vq_prep(const float* __restrict__ cb,
                                               float* __restrict__ sc,
                                               float* __restrict__ losses) {
#pragma clang fp contract(off)
  {
    int k = blockIdx.x * 256 + threadIdx.x;   // grid 2*256 = 512
    const float* c = cb + (size_t)k * ND;
    float q[ND];
#pragma unroll
    for (int d = 0; d < ND; ++d) q[d] = c[d] * c[d];
    float r[8];
#pragma unroll
    for (int j = 0; j < 8; ++j) r[j] = q[j];
#pragma unroll
    for (int i = 8; i < ND; i += 8)
#pragma unroll
      for (int j = 0; j < 8; ++j) r[j] += q[i + j];
    float res = ((r[0] + r[1]) + (r[2] + r[3])) + ((r[4] + r[5]) + (r[6] + r[7]));
    sc[k] = res;
    if (k < 2) losses[k] = 0.f;
  }
}

// ---------------------------------------------------------------------------
// Main: 64 pixels/block, 4 waves = 4 K-slices of 128 codes. x tile in LDS
// (rounds 2-4: a 64-float per-thread array always spills). Round 5 was
// stall-bound: codebook s_loads (out-of-order SMEM) forced lgkmcnt(0) full
// drains that also killed ds_read pipelining. This round the codebook and sc
// stream through VMEM broadcast loads instead: pointers are laundered through
// an empty asm so the compiler cannot prove them uniform -> global_load
// (vmcnt, in-order, fine-grained waits), independent of the ds_read counter.
// All lanes load the same address -> TA broadcast, 1 transaction, L1/L2-hit.
// Numerics bit-identical to the passing R2 kernel:
//   d2[k] = fl(fl(Sx - fl(2*M[k])) + Sc[k]), M[k] sequential fp32 FMA chain
//   d=0..63, Sx numpy pairwise-8; slice merge ascending, strict '<'
//   => lowest index wins ties = np.argmin over full K.
// ---------------------------------------------------------------------------
__global__ __launch_bounds__(256) void vq_main(const float* __restrict__ x,
                                               const float* __restrict__ cb,
                                               const float* __restrict__ sc,
                                               float* __restrict__ out,
                                               float* __restrict__ idx_out,
                                               float* __restrict__ losses) {
#pragma clang fp contract(off)
  {
    __shared__ float lx[64 * XS];          // 17.4 KB x tile [pixel][d]
    __shared__ float sh_m[4][64];
    __shared__ int sh_i[4][64];
    __shared__ int sh_w[64];
    __shared__ float red[4];

    const int tid = threadIdx.x;
    const int p = tid & 63;                                    // pixel lane
    const int wv = __builtin_amdgcn_readfirstlane(tid >> 6);   // slice, SGPR
    const int b = blockIdx.x >> 6;                             // image
    const int hw0 = (blockIdx.x & 63) << 6;                    // tile base
    const float* xbase = x + (size_t)b * (ND * NHW) + hw0;

    // Laundered (divergent-looking) pointers: force VMEM, not SMEM.
    const float* cbv = cb;
    asm volatile("" : "+v"(cbv));
    const float* scv = sc;
    asm volatile("" : "+v"(scv));

    // ---- Stage x tile: thread (p, wv) loads quads dq = wv, wv+4, wv+8, wv+12.
#pragma unroll
    for (int i = 0; i < 4; ++i) {
      const int dq = wv + i * 4;
      const int d = dq * 4;
      float4 q;
      q.x = xbase[(size_t)(d + 0) * NHW + p];
      q.y = xbase[(size_t)(d + 1) * NHW + p];
      q.z = xbase[(size_t)(d + 2) * NHW + p];
      q.w = xbase[(size_t)(d + 3) * NHW + p];
      *(float4*)&lx[p * XS + d] = q;
    }
    __syncthreads();

    // ---- Sx = np.sum(x*x): rounded squares, pairwise-8 (bitwise = R2).
    float r[8];
    {
      float4 q0 = *(const float4*)&lx[p * XS + 0];
      float4 q1 = *(const float4*)&lx[p * XS + 4];
      r[0] = q0.x * q0.x; r[1] = q0.y * q0.y; r[2] = q0.z * q0.z; r[3] = q0.w * q0.w;
      r[4] = q1.x * q1.x; r[5] = q1.y * q1.y; r[6] = q1.z * q1.z; r[7] = q1.w * q1.w;
#pragma unroll
      for (int i = 2; i < 16; i += 2) {
        float4 a = *(const float4*)&lx[p * XS + i * 4];
        float4 c = *(const float4*)&lx[p * XS + i * 4 + 4];
        r[0] += a.x * a.x; r[1] += a.y * a.y; r[2] += a.z * a.z; r[3] += a.w * a.w;
        r[4] += c.x * c.x; r[5] += c.y * c.y; r[6] += c.z * c.z; r[7] += c.w * c.w;
      }
    }
    const float Sx = ((r[0] + r[1]) + (r[2] + r[3])) + ((r[4] + r[5]) + (r[6] + r[7]));

    // ---- K-slice [wv*128, wv*128+128), 8 code-chains per group.
    const int k0 = wv << 7;
    float m1 = 3.0e38f;
    int i1 = k0;

    for (int kk = 0; kk < 128; kk += 8) {
      const int k = k0 + kk;
      const float* cg = cbv + (size_t)k * ND;   // one VGPR base; code j at
                                                // +j*256B, dq at +16B (imm)
      float a0 = 0.f, a1 = 0.f, a2 = 0.f, a3 = 0.f;
      float a4 = 0.f, a5 = 0.f, a6 = 0.f, a7 = 0.f;
#pragma unroll
      for (int dq = 0; dq < 16; ++dq) {
        const float4 xq = *(const float4*)&lx[p * XS + dq * 4];
        const int d = dq * 4;
#define VQ_STEP(J, AJ)                                                        \
        {                                                                     \
          const float4 cq = *(const float4*)(cg + J * ND + d);                \
          AJ = __builtin_fmaf(cq.x, xq.x, AJ);                                \
          AJ = __builtin_fmaf(cq.y, xq.y, AJ);                                \
          AJ = __builtin_fmaf(cq.z, xq.z, AJ);                                \
          AJ = __builtin_fmaf(cq.w, xq.w, AJ);                                \
        }
        VQ_STEP(0, a0) VQ_STEP(1, a1) VQ_STEP(2, a2) VQ_STEP(3, a3)
        VQ_STEP(4, a4) VQ_STEP(5, a5) VQ_STEP(6, a6) VQ_STEP(7, a7)
#undef VQ_STEP
      }
      float d2v[8];
      d2v[0] = (Sx - 2.0f * a0) + scv[k + 0];
      d2v[1] = (Sx - 2.0f * a1) + scv[k + 1];
      d2v[2] = (Sx - 2.0f * a2) + scv[k + 2];
      d2v[3] = (Sx - 2.0f * a3) + scv[k + 3];
      d2v[4] = (Sx - 2.0f * a4) + scv[k + 4];
      d2v[5] = (Sx - 2.0f * a5) + scv[k + 5];
      d2v[6] = (Sx - 2.0f * a6) + scv[k + 6];
      d2v[7] = (Sx - 2.0f * a7) + scv[k + 7];
#pragma unroll
      for (int j = 0; j < 8; ++j)
        if (d2v[j] < m1) { m1 = d2v[j]; i1 = k + j; }   // in-order ties
    }

    // ---- Merge 4 slices per pixel, ascending slice order, strict '<'.
    sh_m[wv][p] = m1;
    sh_i[wv][p] = i1;
    __syncthreads();
    if (wv == 0) {
      float mm = sh_m[0][p];
      int ii = sh_i[0][p];
#pragma unroll
      for (int s = 1; s < 4; ++s) {
        float ms = sh_m[s][p];
        int is = sh_i[s][p];
        if (ms < mm) { mm = ms; ii = is; }
      }
      sh_w[p] = ii;
      idx_out[blockIdx.x * 64 + p] = (float)ii;   // coalesced
    }
    __syncthreads();
    const int widx = sh_w[p];

    // ---- Epilogue: wave wv writes dims [wv*16, wv*16+16) for its 64 pixels.
    const float4* q4 = (const float4*)(cb + (size_t)widx * ND) + wv * 4;
    float* op = out + (size_t)b * (ND * NHW) + hw0 + p;
    float lossp = 0.f;
#pragma unroll
    for (int j = 0; j < 4; ++j) {
      const float4 q = q4[j];
      const int d = wv * 16 + j * 4;
      const float4 xq = *(const float4*)&lx[p * XS + d];
      float e;
      e = xq.x - q.x; lossp = __builtin_fmaf(e, e, lossp); op[(size_t)(d + 0) * NHW] = q.x;
      e = xq.y - q.y; lossp = __builtin_fmaf(e, e, lossp); op[(size_t)(d + 1) * NHW] = q.y;
      e = xq.z - q.z; lossp = __builtin_fmaf(e, e, lossp); op[(size_t)(d + 2) * NHW] = q.z;
      e = xq.w - q.w; lossp = __builtin_fmaf(e, e, lossp); op[(size_t)(d + 3) * NHW] = q.w;
    }

    // ---- Loss reduction: wave shuffle + LDS + one atomic pair per block.
#pragma unroll
    for (int off = 32; off; off >>= 1) lossp += __shfl_down(lossp, off);
    if (p == 0) red[wv] = lossp;
    __syncthreads();
    if (tid == 0) {
      float t = (red[0] + red[1] + red[2] + red[3]) * (1.f / 8388608.f);
      atomicAdd(losses + 0, t);   // dictionary_loss
      atomicAdd(losses + 1, t);   // commitment_loss (identical forward value)
    }
  }
}

extern "C" void kernel_launch(void* const* d_in, const int* in_sizes, int n_in,
                              void* d_out, int out_size, void* d_ws, size_t ws_size,
                              hipStream_t stream) {
  const float* x  = (const float*)d_in[0];   // [32,64,64,64] fp32
  const float* cb = (const float*)d_in[1];   // [512,64] fp32
  float* out     = (float*)d_out;            // quantized [B,D,H,W]
  float* idx_out = out + OUT_ELEMS;          // indices (as fp32) [B,H,W]
  float* losses  = idx_out + NPIX;           // 2 scalars
  float* sc      = (float*)d_ws;             // 512 floats scratch

  vq_prep<<<2, 256, 0, stream>>>(cb, sc, losses);
  vq_main<<<NPIX / 64, 256, 0, stream>>>(x, cb, sc, out, idx_out, losses);
}

// Round 7
// 260.977 us; speedup vs baseline: 2.0803x; 2.0803x over previous
//
#include <hip/hip_runtime.h>

#define NK 512
#define ND 64
#define NHW 4096
#define NPIX 131072            // 32*64*64
#define OUT_ELEMS 8388608      // 32*64*64*64
#define XS 68                  // LDS x-row stride in floats (16B-aligned, 8-phase banks)

// ---------------------------------------------------------------------------
// Prep: sc[k] = numpy-pairwise-8 fp32 sum of fl(c_d^2); zero the two loss
// slots (harness re-poisons d_out/d_ws to 0xAA before every timed replay).
// ---------------------------------------------------------------------------
__global__ __launch_bounds__(256) void vq_prep(const float* __restrict__ cb,
                                               float* __restrict__ sc,
                                               float* __restrict__ losses) {
#pragma clang fp contract(off)
  {
    int k = blockIdx.x * 256 + threadIdx.x;   // grid 2*256 = 512
    const float* c = cb + (size_t)k * ND;
    float q[ND];
#pragma unroll
    for (int d = 0; d < ND; ++d) q[d] = c[d] * c[d];
    float r[8];
#pragma unroll
    for (int j = 0; j < 8; ++j) r[j] = q[j];
#pragma unroll
    for (int i = 8; i < ND; i += 8)
#pragma unroll
      for (int j = 0; j < 8; ++j) r[j] += q[i + j];
    float res = ((r[0] + r[1]) + (r[2] + r[3])) + ((r[4] + r[5]) + (r[6] + r[7]));
    sc[k] = res;
    if (k < 2) losses[k] = 0.f;
  }
}

// ---------------------------------------------------------------------------
// Main: 64 pixels/block, 4 waves = 4 K-slices of 128 codes.
//  - x tile in LDS (a 64-float per-thread array always spills: R2-R4).
//  - codebook chunks (8 codes = 2 KB) double-buffered through PER-WAVE LDS
//    buffers: 2 coalesced global_load_dwordx4 issued one k-group ahead,
//    ds_write, then broadcast ds_read_b128 (uniform addr, 1 phase) in the
//    K-loop. Same-wave DS ops are in-order -> no barriers in the K-loop.
//  - sc staged to LDS once. K-loop has ZERO SMEM loads (R5: OOO s_load
//    forced lgkmcnt(0) drains) and ZERO per-element VMEM (R6: latency-bound).
// Numerics bit-identical to the passing R2/R5 kernels:
//   d2[k] = fl(fl(Sx - fl(2*M[k])) + Sc[k]), M[k] sequential fp32 FMA chain
//   d=0..63, Sx numpy pairwise-8; slice merge ascending, strict '<'
//   => lowest index wins ties = np.argmin over full K.
// ---------------------------------------------------------------------------
__global__ __launch_bounds__(256) void vq_main(const float* __restrict__ x,
                                               const float* __restrict__ cb,
                                               const float* __restrict__ sc,
                                               float* __restrict__ out,
                                               float* __restrict__ idx_out,
                                               float* __restrict__ losses) {
#pragma clang fp contract(off)
  {
    __shared__ float lx[64 * XS];            // 17.4 KB x tile [pixel][d]
    __shared__ float lcb[4][2][8 * ND];      // 16 KB per-wave dbuf cb chunks
    __shared__ float lsc[NK];                // 2 KB sum-of-squares
    __shared__ float sh_m[4][64];
    __shared__ int sh_i[4][64];
    __shared__ int sh_w[64];
    __shared__ float red[4];

    const int tid = threadIdx.x;
    const int p = tid & 63;                                    // pixel lane
    const int wv = __builtin_amdgcn_readfirstlane(tid >> 6);   // slice, SGPR
    const int b = blockIdx.x >> 6;                             // image
    const int hw0 = (blockIdx.x & 63) << 6;                    // tile base
    const float* xbase = x + (size_t)b * (ND * NHW) + hw0;
    const int k0 = wv << 7;                  // this wave's K-slice base

    // Chunk source: chunk g = codes [k0+8g, k0+8g+8) = float4s [g*128, +128).
    const float4* csrc = (const float4*)(cb + (size_t)k0 * ND);

    // Issue chunk-0 loads as early as possible (coalesced, L2-resident).
    float4 va = csrc[p];
    float4 vb = csrc[64 + p];

    // sc -> LDS (2 floats/thread).
    *(float2*)&lsc[tid * 2] = ((const float2*)sc)[tid];

    // ---- Stage x tile: thread (p,wv) loads quads dq = wv, wv+4, wv+8, wv+12.
#pragma unroll
    for (int i = 0; i < 4; ++i) {
      const int d = (wv + i * 4) * 4;
      float4 q;
      q.x = xbase[(size_t)(d + 0) * NHW + p];
      q.y = xbase[(size_t)(d + 1) * NHW + p];
      q.z = xbase[(size_t)(d + 2) * NHW + p];
      q.w = xbase[(size_t)(d + 3) * NHW + p];
      *(float4*)&lx[p * XS + d] = q;
    }

    // Write chunk 0 into buf 0 (per-wave; no barrier needed), load chunk 1.
    *(float4*)&lcb[wv][0][p * 4] = va;
    *(float4*)&lcb[wv][0][256 + p * 4] = vb;
    va = csrc[128 + p];
    vb = csrc[192 + p];

    __syncthreads();   // x tile visible to all waves

    // ---- Sx = np.sum(x*x): rounded squares, pairwise-8 (bitwise = R2).
    float r[8];
    {
      float4 q0 = *(const float4*)&lx[p * XS + 0];
      float4 q1 = *(const float4*)&lx[p * XS + 4];
      r[0] = q0.x * q0.x; r[1] = q0.y * q0.y; r[2] = q0.z * q0.z; r[3] = q0.w * q0.w;
      r[4] = q1.x * q1.x; r[5] = q1.y * q1.y; r[6] = q1.z * q1.z; r[7] = q1.w * q1.w;
#pragma unroll
      for (int i = 2; i < 16; i += 2) {
        float4 a = *(const float4*)&lx[p * XS + i * 4];
        float4 c = *(const float4*)&lx[p * XS + i * 4 + 4];
        r[0] += a.x * a.x; r[1] += a.y * a.y; r[2] += a.z * a.z; r[3] += a.w * a.w;
        r[4] += c.x * c.x; r[5] += c.y * c.y; r[6] += c.z * c.z; r[7] += c.w * c.w;
      }
    }
    const float Sx = ((r[0] + r[1]) + (r[2] + r[3])) + ((r[4] + r[5]) + (r[6] + r[7]));

    // ---- K-loop: 16 chunks of 8 codes, double-buffered through LDS.
    float m1 = 3.0e38f;
    int i1 = k0;

    for (int g = 0; g < 16; ++g) {
      const int cur = g & 1;
      const int k = k0 + g * 8;
      if (g < 15) {
        // Stage chunk g+1 (regs loaded one group ago; vmcnt wait is here).
        *(float4*)&lcb[wv][cur ^ 1][p * 4] = va;
        *(float4*)&lcb[wv][cur ^ 1][256 + p * 4] = vb;
        if (g < 14) {                         // issue chunk g+2 loads
          va = csrc[(g + 2) * 128 + p];
          vb = csrc[(g + 2) * 128 + 64 + p];
        }
      }
      const float* cbuf = lcb[wv][cur];
      float a0 = 0.f, a1 = 0.f, a2 = 0.f, a3 = 0.f;
      float a4 = 0.f, a5 = 0.f, a6 = 0.f, a7 = 0.f;
#pragma unroll
      for (int dq = 0; dq < 16; ++dq) {
        const float4 xq = *(const float4*)&lx[p * XS + dq * 4];
        const int d = dq * 4;
#define VQ_STEP(J, AJ)                                                        \
        {                                                                     \
          const float4 cq = *(const float4*)&cbuf[J * ND + d];  /* broadcast */\
          AJ = __builtin_fmaf(cq.x, xq.x, AJ);                                \
          AJ = __builtin_fmaf(cq.y, xq.y, AJ);                                \
          AJ = __builtin_fmaf(cq.z, xq.z, AJ);                                \
          AJ = __builtin_fmaf(cq.w, xq.w, AJ);                                \
        }
        VQ_STEP(0, a0) VQ_STEP(1, a1) VQ_STEP(2, a2) VQ_STEP(3, a3)
        VQ_STEP(4, a4) VQ_STEP(5, a5) VQ_STEP(6, a6) VQ_STEP(7, a7)
#undef VQ_STEP
      }
      float d2v[8];
      d2v[0] = (Sx - 2.0f * a0) + lsc[k + 0];
      d2v[1] = (Sx - 2.0f * a1) + lsc[k + 1];
      d2v[2] = (Sx - 2.0f * a2) + lsc[k + 2];
      d2v[3] = (Sx - 2.0f * a3) + lsc[k + 3];
      d2v[4] = (Sx - 2.0f * a4) + lsc[k + 4];
      d2v[5] = (Sx - 2.0f * a5) + lsc[k + 5];
      d2v[6] = (Sx - 2.0f * a6) + lsc[k + 6];
      d2v[7] = (Sx - 2.0f * a7) + lsc[k + 7];
#pragma unroll
      for (int j = 0; j < 8; ++j)
        if (d2v[j] < m1) { m1 = d2v[j]; i1 = k + j; }   // in-order ties
    }

    // ---- Merge 4 slices per pixel, ascending slice order, strict '<'.
    sh_m[wv][p] = m1;
    sh_i[wv][p] = i1;
    __syncthreads();
    if (wv == 0) {
      float mm = sh_m[0][p];
      int ii = sh_i[0][p];
#pragma unroll
      for (int s = 1; s < 4; ++s) {
        float ms = sh_m[s][p];
        int is = sh_i[s][p];
        if (ms < mm) { mm = ms; ii = is; }
      }
      sh_w[p] = ii;
      idx_out[blockIdx.x * 64 + p] = (float)ii;   // coalesced
    }
    __syncthreads();
    const int widx = sh_w[p];

    // ---- Epilogue: wave wv writes dims [wv*16, wv*16+16) for its 64 pixels.
    const float4* q4 = (const float4*)(cb + (size_t)widx * ND) + wv * 4;
    float* op = out + (size_t)b * (ND * NHW) + hw0 + p;
    float lossp = 0.f;
#pragma unroll
    for (int j = 0; j < 4; ++j) {
      const float4 q = q4[j];
      const int d = wv * 16 + j * 4;
      const float4 xq = *(const float4*)&lx[p * XS + d];
      float e;
      e = xq.x - q.x; lossp = __builtin_fmaf(e, e, lossp); op[(size_t)(d + 0) * NHW] = q.x;
      e = xq.y - q.y; lossp = __builtin_fmaf(e, e, lossp); op[(size_t)(d + 1) * NHW] = q.y;
      e = xq.z - q.z; lossp = __builtin_fmaf(e, e, lossp); op[(size_t)(d + 2) * NHW] = q.z;
      e = xq.w - q.w; lossp = __builtin_fmaf(e, e, lossp); op[(size_t)(d + 3) * NHW] = q.w;
    }

    // ---- Loss reduction: wave shuffle + LDS + one atomic pair per block.
#pragma unroll
    for (int off = 32; off; off >>= 1) lossp += __shfl_down(lossp, off);
    if (p == 0) red[wv] = lossp;
    __syncthreads();
    if (tid == 0) {
      float t = (red[0] + red[1] + red[2] + red[3]) * (1.f / 8388608.f);
      atomicAdd(losses + 0, t);   // dictionary_loss
      atomicAdd(losses + 1, t);   // commitment_loss (identical forward value)
    }
  }
}

extern "C" void kernel_launch(void* const* d_in, const int* in_sizes, int n_in,
                              void* d_out, int out_size, void* d_ws, size_t ws_size,
                              hipStream_t stream) {
  const float* x  = (const float*)d_in[0];   // [32,64,64,64] fp32
  const float* cb = (const float*)d_in[1];   // [512,64] fp32
  float* out     = (float*)d_out;            // quantized [B,D,H,W]
  float* idx_out = out + OUT_ELEMS;          // indices (as fp32) [B,H,W]
  float* losses  = idx_out + NPIX;           // 2 scalars
  float* sc      = (float*)d_ws;             // 512 floats scratch

  vq_prep<<<2, 256, 0, stream>>>(cb, sc, losses);
  vq_main<<<NPIX / 64, 256, 0, stream>>>(x, cb, sc, out, idx_out, losses);
}